// Round 9
// baseline (110.658 us; speedup 1.0000x reference)
//
#include <hip/hip_runtime.h>
#include <hip/hip_bf16.h>

// CapsuleLayer dynamic routing, MI355X. fp32 in/out.
// C=10, B=128, N=1152, IN=8, OUT=16, 3 routing iters.
//
// v16 (round 19): v14 base + 2-deep software-pipelined priors.
//   History: v11(755MB,occ62) == v13(378MB,occ29) == v14(755MB,occ34) == 42us;
//   v15 (378MB, VGPR108, occ17) = 50us -> additive-pipe model dead; no pipe
//   saturated; time = per-wave serial latency chains x ~5 block rounds.
//   The unattacked chain: sched_barrier(0) between priors passes serializes
//   pass p+1's loads behind pass p's consume -> per pass: issue 10 loads,
//   vmcnt(0), 64 FMA. Exposed L2 latency ~250cyc x 9 = 2250 cyc/wave, NOT
//   covered (only ~2-3 waves/SIMD resident, all versions). v16: 2-deep reg
//   double-buffer: group = {issue loads(p+1); compute(p)}; sched_barrier(0)
//   per group keeps pipeline exactly 2-deep (no r5-r9 balloon). Compiler
//   emits counted vmcnt (~10) instead of drain; each pass's loads get a
//   compute-group (~160cyc) to land. wbuf[2][8]/xbuf[2][2] parity arrays:
//   static indices after full unroll (v13/v14-proven: stays in registers).
//   Peak ~115 VGPR. Prediction: dispatch 35-39us, WRITE stays 80KB.
//   Falsifier: 41-43 flat -> priors latency not a serial term; concede
//   structural floor next round.
//
// Structure: G=1, 512 thr = 8 waves, one block per (c,b), 1280 blocks.
//   Lane l: o-quad q=l&3 (owns o=q*4..+3), row-sub rsub=l>>2; wave w covers
//   rows [w*144,(w+1)*144) in 9 passes of 16. W float4 load = 16 rows x 64 B
//   fully-consumed lines. fp32 accumulation; P bf16x2 in 18 VGPRs (absmax
//   0.0059, threshold 0.0172). Logit recomputed per iter from oa (quad
//   butterfly, 2 shfl). Unnormalized softmax (|logit|<~30, fp32-safe).
//   Iter-0 sums fused into priors. XCD-chunked swizzle: 1280 = 8x160.

constexpr int C = 10, B = 128, N = 1152, IN = 8, OUT = 16;
constexpr int THREADS = 512;
constexpr int NW = THREADS / 64;          // 8 waves
constexpr int PASSES = N / (NW * 16);     // 9
constexpr int NBLK = C * B;               // 1280
constexpr int NXCD = 8;
constexpr int CHUNK = NBLK / NXCD;        // 160 (1280 % 8 == 0: bijective)

__device__ __forceinline__ unsigned packbf(float a, float b) {
    __hip_bfloat162 h = __float22bfloat162_rn(float2{a, b});  // RNE
    return *(unsigned*)&h;
}
__device__ __forceinline__ float bflo(unsigned u) { return __uint_as_float(u << 16); }
__device__ __forceinline__ float bfhi(unsigned u) { return __uint_as_float(u & 0xffff0000u); }

__global__ __launch_bounds__(THREADS)
void caps_route(const float* __restrict__ Xf, const float* __restrict__ Wf,
                float* __restrict__ Of) {
    // combine buffer: [w][0..15] = s4 by o, [16] = ssum, [17..19] pad
    __shared__ float lds_c[NW][20];                    // 640 B

    const int t = threadIdx.x;
    const int l = t & 63;
    const int wid = t >> 6;
    const int q = l & 3;        // o-quad: owns o = q*4 .. q*4+3
    const int rsub = l >> 2;    // row-sub within a pass (0..15)

    // XCD-chunked swizzle: physical bid%8 -> XCD (round-robin dispatch).
    const int bid = blockIdx.x;
    const int blk = (bid & (NXCD - 1)) * CHUNK + (bid >> 3);
    const int c = blk >> 7;     // 128 consecutive logical blocks share c
    const int b = blk & 127;

    // ---- priors: P[n][o] = sum_i x[b,n,i] * W[c,n,i,o]
    // 2-deep pipelined: issue pass p+1's loads before computing pass p.
    // wbuf/xbuf parity arrays: indices compile-time after full unroll.
    uint2 Pr[PASSES];
    float s40[4] = {0.f, 0.f, 0.f, 0.f};
    const int nbase = wid * (16 * PASSES) + rsub;

    float4 wbuf[2][8];
    float4 xbuf[2][2];
    {   // prologue: load pass 0 into buffer 0
        const float4* wr = (const float4*)(Wf + (size_t)(c * N + nbase) * (IN * OUT)) + q;
        #pragma unroll
        for (int i = 0; i < 8; ++i) wbuf[0][i] = wr[i * 4];
        const float4* xr = (const float4*)(Xf + (size_t)(b * N + nbase) * IN);
        xbuf[0][0] = xr[0]; xbuf[0][1] = xr[1];
    }
    #pragma unroll
    for (int p = 0; p < PASSES; ++p) {
        const int cur = p & 1, nxt = cur ^ 1;
        if (p + 1 < PASSES) {   // issue next pass's loads (stay in flight)
            const int n = nbase + (p + 1) * 16;
            const float4* wr = (const float4*)(Wf + (size_t)(c * N + n) * (IN * OUT)) + q;
            #pragma unroll
            for (int i = 0; i < 8; ++i) wbuf[nxt][i] = wr[i * 4];
            const float4* xr = (const float4*)(Xf + (size_t)(b * N + n) * IN);
            xbuf[nxt][0] = xr[0]; xbuf[nxt][1] = xr[1];
        }
        // compute pass p from buffer cur
        const float xs[8] = { xbuf[cur][0].x, xbuf[cur][0].y,
                              xbuf[cur][0].z, xbuf[cur][0].w,
                              xbuf[cur][1].x, xbuf[cur][1].y,
                              xbuf[cur][1].z, xbuf[cur][1].w };
        float a0 = 0.f, a1 = 0.f, a2 = 0.f, a3 = 0.f;
        #pragma unroll
        for (int i = 0; i < 8; ++i) {
            a0 = fmaf(xs[i], wbuf[cur][i].x, a0);
            a1 = fmaf(xs[i], wbuf[cur][i].y, a1);
            a2 = fmaf(xs[i], wbuf[cur][i].z, a2);
            a3 = fmaf(xs[i], wbuf[cur][i].w, a3);
        }
        s40[0] += a0; s40[1] += a1; s40[2] += a2; s40[3] += a3;
        Pr[p] = uint2{packbf(a0, a1), packbf(a2, a3)};
        __builtin_amdgcn_sched_barrier(0);   // keep pipeline exactly 2-deep
    }

    // accumulated output quad-slice (fp32); logit[p] == dot(oa_full16, P[p])
    float oa[4] = {0.f, 0.f, 0.f, 0.f};

    // ---- dynamic routing ----
    for (int it = 0; it < 3; ++it) {
        float s4[4];
        float ssum;
        if (it == 0) {
            ssum = (float)PASSES;
            #pragma unroll
            for (int k = 0; k < 4; ++k) s4[k] = s40[k];
        } else {
            ssum = 0.f;
            #pragma unroll
            for (int k = 0; k < 4; ++k) s4[k] = 0.f;
            #pragma unroll
            for (int p = 0; p < PASSES; ++p) {
                const uint2 v = Pr[p];            // register P: pure VALU
                const float p0 = bflo(v.x), p1 = bfhi(v.x);
                const float p2 = bflo(v.y), p3 = bfhi(v.y);
                float d = oa[0] * p0;
                d = fmaf(oa[1], p1, d);
                d = fmaf(oa[2], p2, d);
                d = fmaf(oa[3], p3, d);
                d += __shfl_xor(d, 1, 64);
                d += __shfl_xor(d, 2, 64);
                const float e = __expf(d);        // replicated across quad
                ssum += e;
                s4[0] = fmaf(e, p0, s4[0]);
                s4[1] = fmaf(e, p1, s4[1]);
                s4[2] = fmaf(e, p2, s4[2]);
                s4[3] = fmaf(e, p3, s4[3]);
            }
        }
        // reduce across the 16 row-subs of the wave (masks 4..32; quad bits
        // 0,1 carry replicas (ssum) / distinct o (s4) -> not summed)
        #pragma unroll
        for (int m = 4; m < 64; m <<= 1) {
            ssum += __shfl_xor(ssum, m, 64);
            #pragma unroll
            for (int k = 0; k < 4; ++k) s4[k] += __shfl_xor(s4[k], m, 64);
        }
        if (l < 4) {  // lane l == quad q: owns o = l*4..l*4+3
            #pragma unroll
            for (int k = 0; k < 4; ++k) lds_c[wid][l * 4 + k] = s4[k];
        }
        if (l == 0) lds_c[wid][16] = ssum;
        __syncthreads();   // A: combine buffer ready

        // all-thread redundant combine + squash (each thread: its own o-quad).
        // lds_c reads: 4 distinct 16B addrs/wave -> 16-lane broadcast, free.
        float a0 = 0.f, a1 = 0.f, a2 = 0.f, a3 = 0.f, S = 0.f;
        #pragma unroll
        for (int w = 0; w < NW; ++w) {
            const float4 v = *(const float4*)&lds_c[w][q * 4];
            a0 += v.x; a1 += v.y; a2 += v.z; a3 += v.w;
            S += lds_c[w][16];
        }
        const float inv = 1.f / S;
        const float s0 = a0 * inv, s1 = a1 * inv;
        const float s2 = a2 * inv, s3 = a3 * inv;
        float r = s0 * s0 + s1 * s1 + s2 * s2 + s3 * s3;
        r += __shfl_xor(r, 1, 64);
        r += __shfl_xor(r, 2, 64);
        const float sc = r / ((1.f + r) * sqrtf(r + 1e-8f));
        if (it < 2) {
            __syncthreads();   // B: combine reads done before next writes
            oa[0] += s0 * sc; oa[1] += s1 * sc;
            oa[2] += s2 * sc; oa[3] += s3 * sc;
        } else if (t < 4) {  // wid==0, rsub==0, q==t: write final outputs
            Of[((size_t)c * B + b) * OUT + q * 4 + 0] = s0 * sc;
            Of[((size_t)c * B + b) * OUT + q * 4 + 1] = s1 * sc;
            Of[((size_t)c * B + b) * OUT + q * 4 + 2] = s2 * sc;
            Of[((size_t)c * B + b) * OUT + q * 4 + 3] = s3 * sc;
        }
    }
}

extern "C" void kernel_launch(void* const* d_in, const int* in_sizes, int n_in,
                              void* d_out, int out_size, void* d_ws, size_t ws_size,
                              hipStream_t stream) {
    const float* X = (const float*)d_in[0];   // [B,N,IN] fp32
    const float* W = (const float*)d_in[1];   // [C,N,IN,OUT] fp32
    float* O = (float*)d_out;                 // [C,B,OUT] fp32
    hipLaunchKernelGGL(caps_route, dim3(NBLK), dim3(THREADS), 0, stream, X, W, O);
}